// Round 1
// baseline (160.325 us; speedup 1.0000x reference)
//
#include <hip/hip_runtime.h>
#include <math.h>

// BCE + distance-correlation (DisCo) loss, N=8192 fp32.
// disco = S_AB / sqrt(S_AA*S_BB) with S_XY = sum_ij X_ij Y_ij nw_i nw_j,
// A_ij = |x_i-x_j| - aavg_i - aavg_j + c_a  (double-centered distance mat).
//
// ws layout: doubles[0..6] = {wsum, bce_sum, ca_sum, cb_sum, S_AB, S_AA, S_BB}
//            then float aavg[N], float bavg[N] at byte offset 64.

__device__ inline double waveReduce(double v) {
    for (int off = 32; off > 0; off >>= 1) v += __shfl_down(v, off, 64);
    return v;
}

// valid in threadIdx.x==0
__device__ inline double blockReduce(double v, double* lds) {
    int tid = threadIdx.x;
    int lane = tid & 63, wid = tid >> 6;
    v = waveReduce(v);
    if (lane == 0) lds[wid] = v;
    __syncthreads();
    double r = 0.0;
    if (wid == 0) {
        int nw = blockDim.x >> 6;
        r = (lane < nw) ? lds[lane] : 0.0;
        r = waveReduce(r);
    }
    __syncthreads();   // make lds reusable for a following call
    return r;
}

// Pass 1: wsum and bce sum.
__global__ void k1_reduce(const float* __restrict__ x, const float* __restrict__ lab,
                          const float* __restrict__ wts, int n, double* wsd) {
    __shared__ double lds[8];
    int tid = blockIdx.x * blockDim.x + threadIdx.x;
    int stride = gridDim.x * blockDim.x;
    double wsum = 0.0, bsum = 0.0;
    for (int i = tid; i < n; i += stride) {
        float w = wts[i];
        float xi = x[i];
        float yi = lab[i];
        // logaddexp(0,x) = softplus(x), stable
        float sp = fmaxf(xi, 0.0f) + log1pf(expf(-fabsf(xi)));
        wsum += (double)w;
        bsum += (double)((sp - xi * yi) * w);
    }
    wsum = blockReduce(wsum, lds);
    bsum = blockReduce(bsum, lds);
    if (threadIdx.x == 0) {
        atomicAdd(&wsd[0], wsum);
        atomicAdd(&wsd[1], bsum);
    }
}

// Pass 2: per-row weighted mean of |x_i - x_j| (and event). One block per row.
__global__ void k2_rowavg(const float* __restrict__ x, const float* __restrict__ e,
                          const float* __restrict__ wts, int n, const double* wsd,
                          float* __restrict__ aavg, float* __restrict__ bavg) {
    __shared__ double lds[8];
    int i = blockIdx.x;
    float scale = (float)((double)n / wsd[0]);   // nw_j = wts_j * scale
    float xi = x[i], ei = e[i];
    float fa = 0.0f, fb = 0.0f;                  // <=32 terms per thread in fp32: safe
    for (int j = threadIdx.x; j < n; j += blockDim.x) {
        float wj = wts[j] * scale;
        fa += fabsf(xi - x[j]) * wj;
        fb += fabsf(ei - e[j]) * wj;
    }
    double sa = blockReduce((double)fa, lds);
    double sb = blockReduce((double)fb, lds);
    if (threadIdx.x == 0) {
        aavg[i] = (float)(sa / n);
        bavg[i] = (float)(sb / n);
    }
}

// Pass 3: ca_sum = sum_i aavg_i*nw_i (single block, no atomics).
__global__ void k3_csum(const float* __restrict__ aavg, const float* __restrict__ bavg,
                        const float* __restrict__ wts, int n, double* wsd) {
    __shared__ double lds[8];
    float scale = (float)((double)n / wsd[0]);
    double sa = 0.0, sb = 0.0;
    for (int i = threadIdx.x; i < n; i += blockDim.x) {
        float nwi = wts[i] * scale;
        sa += (double)(aavg[i] * nwi);
        sb += (double)(bavg[i] * nwi);
    }
    sa = blockReduce(sa, lds);
    sb = blockReduce(sb, lds);
    if (threadIdx.x == 0) { wsd[2] = sa; wsd[3] = sb; }
}

// Pass 4: main N^2 pass, LDS-staged j-chunks. Each thread owns row i over a
// j-subrange; fp32 accumulation is bounded to one 256-chunk then promoted.
#define CH 256
__global__ void k4_main(const float* __restrict__ x, const float* __restrict__ e,
                        const float* __restrict__ wts,
                        const float* __restrict__ aavg, const float* __restrict__ bavg,
                        int n, int jlen, double* wsd) {
    __shared__ float xs[CH], es[CH], ws_[CH], as_[CH], bs_[CH];
    __shared__ double lds[8];
    int i = blockIdx.x * blockDim.x + threadIdx.x;
    float scale = (float)((double)n / wsd[0]);
    float ca = (float)(wsd[2] / n);
    float cb = (float)(wsd[3] / n);
    bool active = (i < n);
    float xi = 0.f, ei = 0.f, ri = 0.f, si = 0.f;
    if (active) { xi = x[i]; ei = e[i]; ri = aavg[i]; si = bavg[i]; }
    int j0 = blockIdx.y * jlen;
    int j1 = min(n, j0 + jlen);
    double dAB = 0.0, dAA = 0.0, dBB = 0.0;
    for (int jb = j0; jb < j1; jb += CH) {
        int c = min(CH, j1 - jb);
        if ((int)threadIdx.x < c) {
            int j = jb + threadIdx.x;
            xs[threadIdx.x]  = x[j];
            es[threadIdx.x]  = e[j];
            ws_[threadIdx.x] = wts[j] * scale;
            as_[threadIdx.x] = aavg[j];
            bs_[threadIdx.x] = bavg[j];
        }
        __syncthreads();
        float fAB = 0.f, fAA = 0.f, fBB = 0.f;
        if (active) {
            for (int k = 0; k < c; ++k) {
                float A = fabsf(xi - xs[k]) - ri - as_[k] + ca;
                float B = fabsf(ei - es[k]) - si - bs_[k] + cb;
                float wj = ws_[k];
                float Aw = A * wj;
                fAB += Aw * B;
                fAA += Aw * A;
                fBB += B * wj * B;
            }
        }
        dAB += (double)fAB; dAA += (double)fAA; dBB += (double)fBB;
        __syncthreads();
    }
    float nwi = active ? wts[i] * scale : 0.0f;
    dAB *= (double)nwi; dAA *= (double)nwi; dBB *= (double)nwi;
    dAB = blockReduce(dAB, lds);
    dAA = blockReduce(dAA, lds);
    dBB = blockReduce(dBB, lds);
    if (threadIdx.x == 0) {
        atomicAdd(&wsd[4], dAB);
        atomicAdd(&wsd[5], dAA);
        atomicAdd(&wsd[6], dBB);
    }
}

// Pass 5: finalize.
__global__ void k5_final(const double* __restrict__ wsd, int n, float* __restrict__ out) {
    double bce = wsd[1] / n;
    double disco = wsd[4] / sqrt(wsd[5] * wsd[6]);
    out[0] = (float)bce;
    out[1] = (float)disco;
    out[2] = (float)(bce + 0.1 * disco);
}

extern "C" void kernel_launch(void* const* d_in, const int* in_sizes, int n_in,
                              void* d_out, int out_size, void* d_ws, size_t ws_size,
                              hipStream_t stream) {
    const float* outputs = (const float*)d_in[0];
    const float* labels  = (const float*)d_in[1];
    const float* event   = (const float*)d_in[2];
    const float* weights = (const float*)d_in[3];
    int n = in_sizes[0];

    double* wsd = (double*)d_ws;
    float* aavg = (float*)((char*)d_ws + 64);
    float* bavg = aavg + n;
    float* out  = (float*)d_out;

    hipMemsetAsync(d_ws, 0, 64, stream);   // zero the 7 double accumulators

    k1_reduce<<<64, 256, 0, stream>>>(outputs, labels, weights, n, wsd);
    k2_rowavg<<<n, 256, 0, stream>>>(outputs, event, weights, n, wsd, aavg, bavg);
    k3_csum<<<1, 256, 0, stream>>>(aavg, bavg, weights, n, wsd);

    const int JS = 8;                       // j-dimension splits
    int jlen = (n + JS - 1) / JS;
    dim3 g4((n + 255) / 256, JS);
    k4_main<<<g4, 256, 0, stream>>>(outputs, event, weights, aavg, bavg, n, jlen, wsd);

    k5_final<<<1, 1, 0, stream>>>(wsd, n, out);
}

// Round 3
// 107.266 us; speedup vs baseline: 1.4946x; 1.4946x over previous
//
#include <hip/hip_runtime.h>
#include <math.h>

// BCE + distance-correlation loss, N=8192 fp32 — single fused N^2 pass.
//
// Algebraic expansion (raw weights w, W=sum w, s=N/W, nw=s*w):
//   S_XY = sum_ij nw_i nw_j X_ij Y_ij  with X = double-centered |x_i-x_j|
//        = s^2*T1xy - (2 s^3/N)*sum_i w_i RX_i RY_i + (s^4/N^2)*CX*CY
//   where T1xy = sum_ij w_i w_j x_ij y_ij,  RX_i = sum_j w_j |x_i-x_j|,
//   CX = sum_i w_i RX_i.   disco = S_AB / sqrt(S_AA*S_BB)  (N^2 cancels).
// One N^2 kernel yields T1{ab,aa,bb} + row sums RA,RB; a single-block
// finalize kernel computes BCE and combines the scalars in double.
//
// ws layout: double[0..2] = {T1ab, T1aa, T1bb}; float RA[N], RB[N] at +64B.

#define BLK  256   // threads per block in the N^2 kernel
#define RPT  4     // rows per thread  -> i-tile = 1024
#define JLEN 128   // j-chunk per block (staged once in LDS)

__device__ inline double waveReduceD(double v) {
    for (int off = 32; off > 0; off >>= 1) v += __shfl_down(v, off, 64);
    return v;
}

// result valid in threadIdx.x==0
__device__ inline double blockReduceD(double v, double* lds) {
    int lane = threadIdx.x & 63, wid = threadIdx.x >> 6;
    v = waveReduceD(v);
    if (lane == 0) lds[wid] = v;
    __syncthreads();
    double r = 0.0;
    if (wid == 0) {
        int nw = blockDim.x >> 6;
        r = (lane < nw) ? lds[lane] : 0.0;
        r = waveReduceD(r);
    }
    __syncthreads();
    return r;
}

// Fused N^2 pass. grid = (n/(BLK*RPT), n/JLEN).
__global__ __launch_bounds__(BLK) void kf(
        const float* __restrict__ x, const float* __restrict__ e,
        const float* __restrict__ w, int n, double* __restrict__ wsd,
        float* __restrict__ RA, float* __restrict__ RB) {
    __shared__ float xs[JLEN], es[JLEN], wsh[JLEN];
    __shared__ double lds[BLK / 64];
    int t = threadIdx.x;
    int j0 = blockIdx.y * JLEN;
    if (t < JLEN) {
        int j = j0 + t;
        xs[t] = x[j]; es[t] = e[j]; wsh[t] = w[j];
    }
    __syncthreads();

    int i0 = blockIdx.x * (BLK * RPT) + t;
    float xi[RPT], ei[RPT], ra[RPT], rb[RPT], ab[RPT], aa[RPT], bb[RPT];
#pragma unroll
    for (int r = 0; r < RPT; ++r) {
        int i = i0 + r * BLK;
        xi[r] = x[i]; ei[r] = e[i];
        ra[r] = 0.f; rb[r] = 0.f;
        ab[r] = 0.f; aa[r] = 0.f; bb[r] = 0.f;
    }

#pragma unroll 4
    for (int k = 0; k < JLEN; ++k) {
        float xj = xs[k], ej = es[k], wj = wsh[k];   // broadcast reads, conflict-free
#pragma unroll
        for (int r = 0; r < RPT; ++r) {
            float a  = fabsf(xi[r] - xj);
            float b  = fabsf(ei[r] - ej);
            float wa = wj * a;
            float wb = wj * b;
            ra[r] += wa;
            rb[r] += wb;
            ab[r] = fmaf(wa, b, ab[r]);     // per-row: w_i applied at the end
            aa[r] = fmaf(wa, a, aa[r]);
            bb[r] = fmaf(wb, b, bb[r]);
        }
    }

    // apply the w_i factor per row, then promote to double
    double tab = 0.0, taa = 0.0, tbb = 0.0;
#pragma unroll
    for (int r = 0; r < RPT; ++r) {
        float wi = w[i0 + r * BLK];
        tab += (double)(wi * ab[r]);
        taa += (double)(wi * aa[r]);
        tbb += (double)(wi * bb[r]);
    }
    tab = blockReduceD(tab, lds);
    taa = blockReduceD(taa, lds);
    tbb = blockReduceD(tbb, lds);
    if (t == 0) {
        atomicAdd(&wsd[0], tab);
        atomicAdd(&wsd[1], taa);
        atomicAdd(&wsd[2], tbb);
    }
#pragma unroll
    for (int r = 0; r < RPT; ++r) {
        atomicAdd(&RA[i0 + r * BLK], ra[r]);
        atomicAdd(&RB[i0 + r * BLK], rb[r]);
    }
}

// Finalize: BCE + all scalar reductions + combine. One block.
__global__ __launch_bounds__(1024) void kg(
        const float* __restrict__ x, const float* __restrict__ lab,
        const float* __restrict__ w, const float* __restrict__ RA,
        const float* __restrict__ RB, int n, const double* __restrict__ wsd,
        float* __restrict__ out) {
    __shared__ double lds[16];
    double sW = 0, sBCE = 0, sAB = 0, sAA = 0, sBB = 0, sCA = 0, sCB = 0;
    for (int i = threadIdx.x; i < n; i += blockDim.x) {
        float wi = w[i];
        float xi = x[i], yi = lab[i];
        float sp = fmaxf(xi, 0.f) + log1pf(expf(-fabsf(xi)));  // softplus, stable
        float rai = RA[i], rbi = RB[i];
        sW   += (double)wi;
        sBCE += (double)((sp - xi * yi) * wi);
        double wra = (double)wi * rai;
        double wrb = (double)wi * rbi;
        sAB += wra * rbi;
        sAA += wra * rai;
        sBB += wrb * rbi;
        sCA += wra;
        sCB += wrb;
    }
    sW   = blockReduceD(sW, lds);
    sBCE = blockReduceD(sBCE, lds);
    sAB  = blockReduceD(sAB, lds);
    sAA  = blockReduceD(sAA, lds);
    sBB  = blockReduceD(sBB, lds);
    sCA  = blockReduceD(sCA, lds);
    sCB  = blockReduceD(sCB, lds);
    if (threadIdx.x == 0) {
        double N  = (double)n;
        double s  = N / sW;
        double s2 = s * s, s3 = s2 * s, s4 = s2 * s2;
        double Sab = s2 * wsd[0] - (2.0 * s3 / N) * sAB + (s4 / (N * N)) * sCA * sCB;
        double Saa = s2 * wsd[1] - (2.0 * s3 / N) * sAA + (s4 / (N * N)) * sCA * sCA;
        double Sbb = s2 * wsd[2] - (2.0 * s3 / N) * sBB + (s4 / (N * N)) * sCB * sCB;
        double disco = Sab / sqrt(Saa * Sbb);
        double bce   = sBCE / N;
        out[0] = (float)bce;
        out[1] = (float)disco;
        out[2] = (float)(bce + 0.1 * disco);
    }
}

extern "C" void kernel_launch(void* const* d_in, const int* in_sizes, int n_in,
                              void* d_out, int out_size, void* d_ws, size_t ws_size,
                              hipStream_t stream) {
    const float* outputs = (const float*)d_in[0];
    const float* labels  = (const float*)d_in[1];
    const float* event   = (const float*)d_in[2];
    const float* weights = (const float*)d_in[3];
    int n = in_sizes[0];

    double* wsd = (double*)d_ws;
    float* RA = (float*)((char*)d_ws + 64);
    float* RB = RA + n;
    float* out = (float*)d_out;

    hipMemsetAsync(d_ws, 0, 64 + (size_t)2 * n * sizeof(float), stream);

    dim3 gF(n / (BLK * RPT), n / JLEN);        // (8, 64) = 512 blocks
    kf<<<gF, BLK, 0, stream>>>(outputs, event, weights, n, wsd, RA, RB);
    kg<<<1, 1024, 0, stream>>>(outputs, labels, weights, RA, RB, n, wsd, out);
}